// Round 4
// baseline (217.450 us; speedup 1.0000x reference)
//
#include <hip/hip_runtime.h>

// DecodeBox: B=16, A=3, ATTRS=6, D=H=W=48, stride=2 everywhere.
// in : [B, A*ATTRS, D, H, W] fp32   (channel stride = 110592 floats = 432 KB)
// out: [B, A*D*H*W, 6] fp32
//
// R3 structure (deep-pipelined streaming):
//  - 1296 blocks x 256 threads; each block processes 4 tiles of 1024 sites.
//    108 tiles/plane = 27 blocks x 4 -> no block straddles a (b,a) plane;
//    plane/anchor math hoisted out of the tile loop.
//  - Software pipeline depth 1 across tiles: tile t+1's 6 nt-loads are in
//    flight during tile t's compute + LDS transpose + nt-stores. Barriers
//    are raw s_barrier + lgkmcnt(0) only (no vmcnt drain), so prefetched
//    global loads stay outstanding across barriers. 75% of tiles fully
//    overlapped (vs 50% at TPB=2 in R2).
//  - LDS 24 KB single-buffer (6 blocks/CU -> 24 waves/CU of TLP).

typedef float vf4 __attribute__((ext_vector_type(4)));

#define DHW    110592   // sites per (b,a) plane
#define HW48   2304
#define SPB    1024     // sites per tile
#define BPP    108      // tiles per plane
#define F4B    1536     // float4s per tile (1024*6/4)
#define F4P    165888   // float4s per plane
#define CH4    27648    // channel stride in float4 units (DHW/4)
#define TPB    4        // tiles per block
#define NBLK   1296     // 5184 tiles / 4

struct Frag { vf4 x, y, z, l, c, k; };

__device__ __forceinline__ float sigm(float v) {
    return 1.0f / (1.0f + __expf(-v));
}

// float4-granular XOR swizzle: lane-linear reads conflict-free, stride-6
// writes spread over all 8 4-bank groups.
__device__ __forceinline__ int swz(int i) {
    return (i & ~7) | ((i ^ (i >> 3)) & 7);
}

// barrier that waits LDS ops only -- leaves global loads/stores in flight
__device__ __forceinline__ void lds_barrier() {
    asm volatile("s_waitcnt lgkmcnt(0)" ::: "memory");
    __builtin_amdgcn_s_barrier();
}

__device__ __forceinline__ void load_frag(const vf4* __restrict__ pin,
                                          int chunk, int tid, Frag& f) {
    const vf4* ip = pin + chunk * (SPB / 4) + tid;
    f.x = __builtin_nontemporal_load(ip + 0 * CH4);
    f.y = __builtin_nontemporal_load(ip + 1 * CH4);
    f.z = __builtin_nontemporal_load(ip + 2 * CH4);
    f.l = __builtin_nontemporal_load(ip + 3 * CH4);
    f.c = __builtin_nontemporal_load(ip + 4 * CH4);
    f.k = __builtin_nontemporal_load(ip + 5 * CH4);
}

__device__ __forceinline__ void process(vf4* __restrict__ pout, int chunk,
                                        int tid, float anchw, const Frag& f,
                                        vf4* lds) {
    const int S = chunk * SPB + tid * 4;      // first of 4 consecutive sites
    const float xf = (float)(S % 48);         // S multiple of 4: no row wrap
    const float yf = (float)((S / 48) % 48);
    const float zf = (float)(S / HW48);

    float bx[4], by[4], bz[4], bl[4], cf[4], cl[4];
#pragma unroll
    for (int q = 0; q < 4; ++q) {
        bx[q] = (sigm(f.x[q]) + xf + (float)q) * 2.0f;
        by[q] = (sigm(f.y[q]) + yf) * 2.0f;
        bz[q] = (sigm(f.z[q]) + zf) * 2.0f;
        bl[q] = __expf(f.l[q]) * anchw;  // exp(l) * (anchor_w/stride) * stride
        cf[q] = sigm(f.c[q]);
        cl[q] = sigm(f.k[q]);
    }

    const int wb = 6 * tid;
    lds[swz(wb + 0)] = (vf4){bx[0], by[0], bz[0], bl[0]};
    lds[swz(wb + 1)] = (vf4){cf[0], cl[0], bx[1], by[1]};
    lds[swz(wb + 2)] = (vf4){bz[1], bl[1], cf[1], cl[1]};
    lds[swz(wb + 3)] = (vf4){bx[2], by[2], bz[2], bl[2]};
    lds[swz(wb + 4)] = (vf4){cf[2], cl[2], bx[3], by[3]};
    lds[swz(wb + 5)] = (vf4){bz[3], bl[3], cf[3], cl[3]};

    lds_barrier();   // LDS writes visible; prefetched global loads untouched

    vf4* op = pout + chunk * F4B;
#pragma unroll
    for (int kk = 0; kk < 6; ++kk) {
        const int i = tid + 256 * kk;
        __builtin_nontemporal_store(lds[swz(i)], op + i);
    }

    lds_barrier();   // LDS reads done before next tile overwrites
}

__global__ __launch_bounds__(256) void DecodeBox_kernel(
    const float* __restrict__ in, float* __restrict__ out) {
    __shared__ vf4 lds[F4B];
    const int tid = threadIdx.x;
    const int p   = blockIdx.x / 27;            // (b,a) plane, 0..47
    const int c0  = (blockIdx.x % 27) * TPB;    // first tile chunk in plane
    const int a   = p % 3;
    const float anchw = (a == 0) ? 4.0f : (a == 1) ? 8.0f : 16.0f;

    const vf4* pin = (const vf4*)(in + (size_t)p * (6 * DHW));
    vf4* pout = (vf4*)out + (size_t)p * F4P;

    Frag A, B;
    load_frag(pin, c0, tid, A);
#pragma unroll
    for (int t = 0; t < TPB; ++t) {
        if (t + 1 < TPB) load_frag(pin, c0 + t + 1, tid, B);  // prefetch
        process(pout, c0 + t, tid, anchw, A, lds);
        A = B;  // renamed away by full unroll
    }
}

extern "C" void kernel_launch(void* const* d_in, const int* in_sizes, int n_in,
                              void* d_out, int out_size, void* d_ws, size_t ws_size,
                              hipStream_t stream) {
    const float* in = (const float*)d_in[0];
    float* out = (float*)d_out;
    DecodeBox_kernel<<<NBLK, 256, 0, stream>>>(in, out);
}